// Round 1
// baseline (857.792 us; speedup 1.0000x reference)
//
#include <hip/hip_runtime.h>
#include <math.h>

#define TOK   8192
#define DDIM  1024
#define HDIM  4096
#define NEXP  8
#define CAP   17408   /* 16384 + 8*128 padding, = 136*128 */
#define NMT   136
#define BM    128
#define BN    128
#define BK    32

typedef __attribute__((ext_vector_type(8))) short  bfrag;
typedef __attribute__((ext_vector_type(4))) float  ffrag;

__device__ __forceinline__ unsigned short f2bf(float f) {
  unsigned int u = __float_as_uint(f);
  u = (u + 0x7FFFu + ((u >> 16) & 1u)) >> 16;   // RNE
  return (unsigned short)u;
}

__device__ __forceinline__ void gll16(const unsigned short* g, unsigned short* l) {
  __builtin_amdgcn_global_load_lds(
      (const __attribute__((address_space(1))) unsigned int*)g,
      (__attribute__((address_space(3))) unsigned int*)l,
      16, 0, 0);
}

// ---------------- x fp32 -> bf16 ----------------
__global__ __launch_bounds__(256) void cvt_x_kernel(const float* __restrict__ x,
                                                    unsigned short* __restrict__ xb) {
  int id = blockIdx.x * 256 + threadIdx.x;           // 2M threads, one float4 each
  float4 v = ((const float4*)x)[id];
  ushort4 o = { f2bf(v.x), f2bf(v.y), f2bf(v.z), f2bf(v.w) };
  ((ushort4*)xb)[id] = o;
}

// ---------------- W [R][C] fp32 -> WT [C][R] bf16 (per expert batch z) -------
__global__ __launch_bounds__(256) void transpose_cvt(const float* __restrict__ in,
                                                     unsigned short* __restrict__ out,
                                                     int R, int C) {
  const size_t bo = (size_t)blockIdx.z * R * C;
  in += bo; out += bo;
  int r0 = blockIdx.y * 64, c0 = blockIdx.x * 64;
  __shared__ float t[64][65];
  int tr  = threadIdx.x >> 4;          // 0..15
  int tc4 = (threadIdx.x & 15) * 4;    // 0..60
#pragma unroll
  for (int it = 0; it < 4; ++it) {
    int r = tr + it * 16;
    float4 v = *(const float4*)&in[(size_t)(r0 + r) * C + c0 + tc4];
    t[r][tc4 + 0] = v.x; t[r][tc4 + 1] = v.y; t[r][tc4 + 2] = v.z; t[r][tc4 + 3] = v.w;
  }
  __syncthreads();
#pragma unroll
  for (int it = 0; it < 4; ++it) {
    int oc = tr + it * 16;             // local c (out row)
    int og = tc4;                      // local r group (out cols)
    ushort4 o = { f2bf(t[og + 0][oc]), f2bf(t[og + 1][oc]),
                  f2bf(t[og + 2][oc]), f2bf(t[og + 3][oc]) };
    *(ushort4*)&out[(size_t)(c0 + oc) * R + r0 + og] = o;
  }
}

// ---------------- gate: logits, top-2, softmax, histogram ----------------
__global__ __launch_bounds__(64) void gate_kernel(const float* __restrict__ x,
                                                  const float* __restrict__ Wg,
                                                  const float* __restrict__ bg,
                                                  int* __restrict__ topi,
                                                  float* __restrict__ topw,
                                                  int* __restrict__ cnt) {
  int t = blockIdx.x, l = threadIdx.x;
  const float4* xr = (const float4*)(x + (size_t)t * DDIM);
  const float4* wg = (const float4*)Wg;     // [1024][8] -> 2 float4 per row
  float acc[8];
#pragma unroll
  for (int e = 0; e < 8; ++e) acc[e] = 0.f;
#pragma unroll
  for (int g = 0; g < 4; ++g) {
    float4 xv = xr[l * 4 + g];
    int dbase = l * 16 + g * 4;
    float xs[4] = { xv.x, xv.y, xv.z, xv.w };
#pragma unroll
    for (int c = 0; c < 4; ++c) {
      float4 w0 = wg[(dbase + c) * 2 + 0];
      float4 w1 = wg[(dbase + c) * 2 + 1];
      acc[0] += xs[c] * w0.x; acc[1] += xs[c] * w0.y;
      acc[2] += xs[c] * w0.z; acc[3] += xs[c] * w0.w;
      acc[4] += xs[c] * w1.x; acc[5] += xs[c] * w1.y;
      acc[6] += xs[c] * w1.z; acc[7] += xs[c] * w1.w;
    }
  }
#pragma unroll
  for (int off = 32; off >= 1; off >>= 1)
#pragma unroll
    for (int e = 0; e < 8; ++e) acc[e] += __shfl_down(acc[e], off);
  if (l == 0) {
    float v[8];
#pragma unroll
    for (int e = 0; e < 8; ++e) v[e] = acc[e] + bg[e];
    int i0 = 0;
#pragma unroll
    for (int e = 1; e < 8; ++e) if (v[e] > v[i0]) i0 = e;
    int i1 = -1;
#pragma unroll
    for (int e = 0; e < 8; ++e) if (e != i0 && (i1 < 0 || v[e] > v[i1])) i1 = e;
    float e1 = expf(v[i1] - v[i0]);
    float s = 1.f + e1;
    topi[t * 2 + 0] = i0; topi[t * 2 + 1] = i1;
    topw[t * 2 + 0] = 1.f / s; topw[t * 2 + 1] = e1 / s;
    atomicAdd(&cnt[i0], 1);
    atomicAdd(&cnt[i1], 1);
  }
}

// ---------------- offsets: 128-aligned exclusive scan ----------------
__global__ void scan_kernel(const int* __restrict__ cnt, int* __restrict__ offsets) {
  if (threadIdx.x == 0 && blockIdx.x == 0) {
    int o = 0;
#pragma unroll
    for (int e = 0; e < NEXP; ++e) {
      offsets[e] = o;
      o += ((cnt[e] + 127) >> 7) << 7;
    }
    offsets[NEXP] = o;
  }
}

// ---------------- assign rows ----------------
__global__ __launch_bounds__(256) void assign_kernel(const int* __restrict__ topi,
                                                     const int* __restrict__ offsets,
                                                     int* __restrict__ cursor,
                                                     int* __restrict__ row_of,
                                                     int* __restrict__ token_of) {
  int id = blockIdx.x * 256 + threadIdx.x;   // < 16384
  if (id >= TOK * 2) return;
  int e = topi[id];
  int slot = atomicAdd(&cursor[e], 1);
  int row = offsets[e] + slot;
  row_of[id] = row;
  token_of[row] = id >> 1;
}

// ---------------- grouped GEMM (m97 structure) ----------------
// A: bf16 [rows][K] (INDIRECT: row -> token_of lookup into [TOK][K])
// B: bf16 [NEXP][N][K]  (pre-transposed so k is contiguous)
// GELU path: out = bf16 h[row][N] of gelu(acc + bias); else fp32 y[row][N] of acc + bias.
template<bool INDIRECT, bool GELU>
__global__ __launch_bounds__(256)
void moe_gemm(const unsigned short* __restrict__ A, int lda,
              const unsigned short* __restrict__ B0,
              const float* __restrict__ bias0,
              unsigned short* __restrict__ hout,
              float* __restrict__ yout,
              int N, int K,
              const int* __restrict__ offsets,
              const int* __restrict__ token_of) {
  int row0 = blockIdx.y * BM;
  if (row0 >= offsets[NEXP]) return;
  int e = 0;
  while (row0 >= offsets[e + 1]) ++e;
  const unsigned short* B = B0 + (size_t)e * N * K;
  const float* bias = bias0 + (size_t)e * N;
  int n0 = blockIdx.x * BN;

  __shared__ __align__(16) unsigned short As[2][BM][BK];
  __shared__ __align__(16) unsigned short Bs[2][BN][BK];

  int tid = threadIdx.x;
  int w = tid >> 6, l = tid & 63;
  int s0 = 2 * w, s1 = 2 * w + 1;        // each wave stages 2 of 8 16-row segments
  int rsub = l >> 2;                      // row within segment
  int cgrp = (l & 3) * 8;                 // k offset (8 bf16 = 16B)

  const unsigned short *srcA0, *srcA1;
  if (INDIRECT) {
    int t0 = token_of[row0 + s0 * 16 + rsub];
    int t1 = token_of[row0 + s1 * 16 + rsub];
    if (t0 < 0) t0 = 0;
    if (t1 < 0) t1 = 0;
    srcA0 = A + (size_t)t0 * lda + cgrp;
    srcA1 = A + (size_t)t1 * lda + cgrp;
  } else {
    srcA0 = A + (size_t)(row0 + s0 * 16 + rsub) * lda + cgrp;
    srcA1 = A + (size_t)(row0 + s1 * 16 + rsub) * lda + cgrp;
  }
  const unsigned short* srcB0 = B + (size_t)(n0 + s0 * 16 + rsub) * K + cgrp;
  const unsigned short* srcB1 = B + (size_t)(n0 + s1 * 16 + rsub) * K + cgrp;

  ffrag acc[4][4];
#pragma unroll
  for (int i = 0; i < 4; ++i)
#pragma unroll
    for (int j = 0; j < 4; ++j) acc[i][j] = (ffrag){0.f, 0.f, 0.f, 0.f};

  int lrow = l & 15, kq = l >> 4;
  int wm = w >> 1, wn = w & 1;

  auto stage = [&](int buf, int k0) {
    gll16(srcA0 + k0, &As[buf][s0 * 16][0]);
    gll16(srcA1 + k0, &As[buf][s1 * 16][0]);
    gll16(srcB0 + k0, &Bs[buf][s0 * 16][0]);
    gll16(srcB1 + k0, &Bs[buf][s1 * 16][0]);
  };
  auto compute = [&](int buf) {
    bfrag a[4], b[4];
#pragma unroll
    for (int i = 0; i < 4; ++i)
      a[i] = *(const bfrag*)&As[buf][wm * 64 + i * 16 + lrow][kq * 8];
#pragma unroll
    for (int j = 0; j < 4; ++j)
      b[j] = *(const bfrag*)&Bs[buf][wn * 64 + j * 16 + lrow][kq * 8];
#pragma unroll
    for (int i = 0; i < 4; ++i)
#pragma unroll
      for (int j = 0; j < 4; ++j)
        acc[i][j] = __builtin_amdgcn_mfma_f32_16x16x32_bf16(a[i], b[j], acc[i][j], 0, 0, 0);
  };

  stage(0, 0);
  __syncthreads();
  int nk = K / BK;
  int cur = 0;
  for (int kt = 0; kt < nk; ++kt) {
    if (kt + 1 < nk) stage(cur ^ 1, (kt + 1) * BK);
    compute(cur);
    __syncthreads();
    cur ^= 1;
  }

  int colbase = n0 + wn * 64 + lrow;
  int rowbase = row0 + wm * 64 + kq * 4;
#pragma unroll
  for (int j = 0; j < 4; ++j) {
    int col = colbase + j * 16;
    float bj = bias[col];
#pragma unroll
    for (int i = 0; i < 4; ++i) {
      int row = rowbase + i * 16;
#pragma unroll
      for (int r = 0; r < 4; ++r) {
        float v = acc[i][j][r] + bj;
        if (GELU) {
          v = 0.5f * v * (1.0f + erff(v * 0.70710678f));
          hout[(size_t)(row + r) * N + col] = f2bf(v);
        } else {
          yout[(size_t)(row + r) * N + col] = v;
        }
      }
    }
  }
}

// ---------------- combine ----------------
__global__ __launch_bounds__(256) void combine_kernel(const float* __restrict__ y,
                                                      const int* __restrict__ row_of,
                                                      const float* __restrict__ topw,
                                                      float* __restrict__ out) {
  int t = blockIdx.x;
  int r0 = row_of[t * 2 + 0], r1 = row_of[t * 2 + 1];
  float w0 = topw[t * 2 + 0], w1 = topw[t * 2 + 1];
  const float4* y0 = (const float4*)(y + (size_t)r0 * DDIM);
  const float4* y1 = (const float4*)(y + (size_t)r1 * DDIM);
  float4* o = (float4*)(out + (size_t)t * DDIM);
  int i = threadIdx.x;
  float4 a = y0[i], b = y1[i];
  float4 r = { w0 * a.x + w1 * b.x, w0 * a.y + w1 * b.y,
               w0 * a.z + w1 * b.z, w0 * a.w + w1 * b.w };
  o[i] = r;
}

extern "C" void kernel_launch(void* const* d_in, const int* in_sizes, int n_in,
                              void* d_out, int out_size, void* d_ws, size_t ws_size,
                              hipStream_t stream) {
  const float* x  = (const float*)d_in[0];
  const float* Wg = (const float*)d_in[1];
  const float* bg = (const float*)d_in[2];
  const float* W1 = (const float*)d_in[3];
  const float* b1 = (const float*)d_in[4];
  const float* W2 = (const float*)d_in[5];
  const float* b2 = (const float*)d_in[6];
  float* out = (float*)d_out;

  size_t off = 0;
  char* base = (char*)d_ws;
  auto alloc = [&](size_t bytes) -> void* {
    void* p = base + off;
    off += (bytes + 255) & ~(size_t)255;
    return p;
  };
  unsigned short* xb  = (unsigned short*)alloc((size_t)TOK * DDIM * 2);
  unsigned short* w1t = (unsigned short*)alloc((size_t)NEXP * HDIM * DDIM * 2);
  unsigned short* w2t = (unsigned short*)alloc((size_t)NEXP * DDIM * HDIM * 2);
  unsigned short* h   = (unsigned short*)alloc((size_t)CAP * HDIM * 2);
  float*          y   = (float*)alloc((size_t)CAP * DDIM * 4);
  int*   topi    = (int*)alloc((size_t)TOK * 2 * 4);
  float* topw    = (float*)alloc((size_t)TOK * 2 * 4);
  int*   row_of  = (int*)alloc((size_t)TOK * 2 * 4);
  int*   token_of= (int*)alloc((size_t)CAP * 4);
  int*   cnt     = (int*)alloc(32);
  int*   offsets = (int*)alloc(64);
  int*   cursor  = (int*)alloc(32);
  if (off > ws_size) return;  // workspace too small — fail loudly via mismatch

  hipMemsetAsync(cnt, 0, 32, stream);
  hipMemsetAsync(cursor, 0, 32, stream);
  hipMemsetAsync(token_of, 0xFF, (size_t)CAP * 4, stream);

  cvt_x_kernel<<<(TOK * DDIM / 4) / 256, 256, 0, stream>>>(x, xb);
  transpose_cvt<<<dim3(HDIM / 64, DDIM / 64, NEXP), 256, 0, stream>>>(W1, w1t, DDIM, HDIM);
  transpose_cvt<<<dim3(DDIM / 64, HDIM / 64, NEXP), 256, 0, stream>>>(W2, w2t, HDIM, DDIM);
  gate_kernel<<<TOK, 64, 0, stream>>>(x, Wg, bg, topi, topw, cnt);
  scan_kernel<<<1, 64, 0, stream>>>(cnt, offsets);
  assign_kernel<<<(TOK * 2) / 256, 256, 0, stream>>>(topi, offsets, cursor, row_of, token_of);

  moe_gemm<true, true><<<dim3(HDIM / BN, NMT), 256, 0, stream>>>(
      xb, DDIM, w1t, b1, h, nullptr, HDIM, DDIM, offsets, token_of);
  moe_gemm<false, false><<<dim3(DDIM / BN, NMT), 256, 0, stream>>>(
      h, HDIM, w2t, b2, nullptr, y, DDIM, HDIM, offsets, token_of);

  combine_kernel<<<TOK, 256, 0, stream>>>(y, row_of, topw, out);
}

// Round 2
// 743.573 us; speedup vs baseline: 1.1536x; 1.1536x over previous
//
#include <hip/hip_runtime.h>
#include <math.h>

#define TOK   8192
#define DDIM  1024
#define HDIM  4096
#define NEXP  8
#define CAP   17408   /* 16384 + 8*128 padding, = 136*128 */
#define NMT   136
#define BM    128
#define BN    128
#define BK    32

typedef __attribute__((ext_vector_type(8))) short  bfrag;
typedef __attribute__((ext_vector_type(4))) float  ffrag;
typedef __attribute__((ext_vector_type(8))) unsigned short us8;

__device__ __forceinline__ unsigned short f2bf(float f) {
  unsigned int u = __float_as_uint(f);
  u = (u + 0x7FFFu + ((u >> 16) & 1u)) >> 16;   // RNE
  return (unsigned short)u;
}

__device__ __forceinline__ void gll16(const unsigned short* g, unsigned short* l) {
  __builtin_amdgcn_global_load_lds(
      (const __attribute__((address_space(1))) unsigned int*)g,
      (__attribute__((address_space(3))) unsigned int*)l,
      16, 0, 0);
}

// ---------------- W [R][C] fp32 -> WT [C][R] bf16 (per expert batch z) -------
__global__ __launch_bounds__(256) void transpose_cvt(const float* __restrict__ in,
                                                     unsigned short* __restrict__ out,
                                                     int R, int C) {
  const size_t bo = (size_t)blockIdx.z * R * C;
  in += bo; out += bo;
  int r0 = blockIdx.y * 64, c0 = blockIdx.x * 64;
  __shared__ float t[64][65];
  int tr  = threadIdx.x >> 4;          // 0..15
  int tc4 = (threadIdx.x & 15) * 4;    // 0..60
#pragma unroll
  for (int it = 0; it < 4; ++it) {
    int r = tr + it * 16;
    float4 v = *(const float4*)&in[(size_t)(r0 + r) * C + c0 + tc4];
    t[r][tc4 + 0] = v.x; t[r][tc4 + 1] = v.y; t[r][tc4 + 2] = v.z; t[r][tc4 + 3] = v.w;
  }
  __syncthreads();
#pragma unroll
  for (int it = 0; it < 4; ++it) {
    int oc = tr + it * 16;             // local c (out row)
    int og = tc4;                      // local r group (out cols)
    ushort4 o = { f2bf(t[og + 0][oc]), f2bf(t[og + 1][oc]),
                  f2bf(t[og + 2][oc]), f2bf(t[og + 3][oc]) };
    *(ushort4*)&out[(size_t)(c0 + oc) * R + r0 + og] = o;
  }
}

// ------- gate: logits, top-2, softmax, histogram; fused x fp32->bf16 -------
__global__ __launch_bounds__(64) void gate_kernel(const float* __restrict__ x,
                                                  const float* __restrict__ Wg,
                                                  const float* __restrict__ bg,
                                                  unsigned short* __restrict__ xb,
                                                  int* __restrict__ topi,
                                                  float* __restrict__ topw,
                                                  int* __restrict__ cnt) {
  int t = blockIdx.x, l = threadIdx.x;
  const float4* xr = (const float4*)(x + (size_t)t * DDIM);
  ushort4* xo = (ushort4*)(xb + (size_t)t * DDIM);
  const float4* wg = (const float4*)Wg;     // [1024][8] -> 2 float4 per row
  float acc[8];
#pragma unroll
  for (int e = 0; e < 8; ++e) acc[e] = 0.f;
#pragma unroll
  for (int g = 0; g < 4; ++g) {
    int idx = g * 64 + l;                    // float4 index within the row
    float4 xv = xr[idx];
    xo[idx] = (ushort4){ f2bf(xv.x), f2bf(xv.y), f2bf(xv.z), f2bf(xv.w) };
    int dbase = idx * 4;
    float xs[4] = { xv.x, xv.y, xv.z, xv.w };
#pragma unroll
    for (int c = 0; c < 4; ++c) {
      float4 w0 = wg[(dbase + c) * 2 + 0];
      float4 w1 = wg[(dbase + c) * 2 + 1];
      acc[0] += xs[c] * w0.x; acc[1] += xs[c] * w0.y;
      acc[2] += xs[c] * w0.z; acc[3] += xs[c] * w0.w;
      acc[4] += xs[c] * w1.x; acc[5] += xs[c] * w1.y;
      acc[6] += xs[c] * w1.z; acc[7] += xs[c] * w1.w;
    }
  }
#pragma unroll
  for (int off = 32; off >= 1; off >>= 1)
#pragma unroll
    for (int e = 0; e < 8; ++e) acc[e] += __shfl_down(acc[e], off);
  if (l == 0) {
    float v[8];
#pragma unroll
    for (int e = 0; e < 8; ++e) v[e] = acc[e] + bg[e];
    int i0 = 0;
#pragma unroll
    for (int e = 1; e < 8; ++e) if (v[e] > v[i0]) i0 = e;
    int i1 = -1;
#pragma unroll
    for (int e = 0; e < 8; ++e) if (e != i0 && (i1 < 0 || v[e] > v[i1])) i1 = e;
    float e1 = expf(v[i1] - v[i0]);
    float s = 1.f + e1;
    topi[t * 2 + 0] = i0; topi[t * 2 + 1] = i1;
    topw[t * 2 + 0] = 1.f / s; topw[t * 2 + 1] = e1 / s;
    atomicAdd(&cnt[i0], 1);
    atomicAdd(&cnt[i1], 1);
  }
}

// ---------------- offsets: 128-aligned exclusive scan ----------------
__global__ void scan_kernel(const int* __restrict__ cnt, int* __restrict__ offsets) {
  if (threadIdx.x == 0 && blockIdx.x == 0) {
    int o = 0;
#pragma unroll
    for (int e = 0; e < NEXP; ++e) {
      offsets[e] = o;
      o += ((cnt[e] + 127) >> 7) << 7;
    }
    offsets[NEXP] = o;
  }
}

// ---------------- assign rows ----------------
__global__ __launch_bounds__(256) void assign_kernel(const int* __restrict__ topi,
                                                     const int* __restrict__ offsets,
                                                     int* __restrict__ cursor,
                                                     int* __restrict__ row_of,
                                                     int* __restrict__ token_of) {
  int id = blockIdx.x * 256 + threadIdx.x;   // < 16384
  if (id >= TOK * 2) return;
  int e = topi[id];
  int slot = atomicAdd(&cursor[e], 1);
  int row = offsets[e] + slot;
  row_of[id] = row;
  token_of[row] = id >> 1;
}

// ---------------- grouped GEMM (m97 structure + XCD swizzle) ----------------
// A: bf16 [rows][K] (INDIRECT: row -> token_of lookup into [TOK][K])
// B: bf16 [NEXP][N][K]  (pre-transposed so k is contiguous)
// GELU: h[row][N] = bf16 gelu(acc+bias), LDS-staged coalesced store;
// else: y[row][N] = fp32 acc + bias (direct, already 64B-coalesced).
template<bool INDIRECT, bool GELU>
__global__ __launch_bounds__(256)
void moe_gemm(const unsigned short* __restrict__ A, int lda,
              const unsigned short* __restrict__ B0,
              const float* __restrict__ bias0,
              unsigned short* __restrict__ hout,
              float* __restrict__ yout,
              int N, int K,
              const int* __restrict__ offsets,
              const int* __restrict__ token_of) {
  // XCD-chunked bijective swizzle: consecutive vids (same XCD) share an A row-panel.
  int nwg = gridDim.x * gridDim.y;           // 4352 or 1088, both % 8 == 0
  int orig = blockIdx.y * gridDim.x + blockIdx.x;
  int vid = (orig & 7) * (nwg >> 3) + (orig >> 3);
  int bx = vid % gridDim.x;
  int by = vid / gridDim.x;

  int row0 = by * BM;
  if (row0 >= offsets[NEXP]) return;
  int e = 0;
  while (row0 >= offsets[e + 1]) ++e;
  const unsigned short* B = B0 + (size_t)e * N * K;
  const float* bias = bias0 + (size_t)e * N;
  int n0 = bx * BN;

  // single 32 KB LDS pool: As = [2][BM][BK], Bs = [2][BN][BK]; epilogue reuses
  // the whole pool as a [BM][BN] bf16 staging tile (exactly 16384 ushorts).
  __shared__ __align__(16) unsigned short sm[16384];
#define AS_(buf, r, k) sm[(buf) * (BM * BK) + (r) * BK + (k)]
#define BS_(buf, r, k) sm[2 * (BM * BK) + (buf) * (BN * BK) + (r) * BK + (k)]

  int tid = threadIdx.x;
  int w = tid >> 6, l = tid & 63;
  int s0 = 2 * w, s1 = 2 * w + 1;        // each wave stages 2 of 8 16-row segments
  int rsub = l >> 2;                      // row within segment
  int cgrp = (l & 3) * 8;                 // k offset (8 bf16 = 16B)

  const unsigned short *srcA0, *srcA1;
  if (INDIRECT) {
    int t0 = token_of[row0 + s0 * 16 + rsub];
    int t1 = token_of[row0 + s1 * 16 + rsub];
    if (t0 < 0) t0 = 0;
    if (t1 < 0) t1 = 0;
    srcA0 = A + (size_t)t0 * lda + cgrp;
    srcA1 = A + (size_t)t1 * lda + cgrp;
  } else {
    srcA0 = A + (size_t)(row0 + s0 * 16 + rsub) * lda + cgrp;
    srcA1 = A + (size_t)(row0 + s1 * 16 + rsub) * lda + cgrp;
  }
  const unsigned short* srcB0 = B + (size_t)(n0 + s0 * 16 + rsub) * K + cgrp;
  const unsigned short* srcB1 = B + (size_t)(n0 + s1 * 16 + rsub) * K + cgrp;

  ffrag acc[4][4];
#pragma unroll
  for (int i = 0; i < 4; ++i)
#pragma unroll
    for (int j = 0; j < 4; ++j) acc[i][j] = (ffrag){0.f, 0.f, 0.f, 0.f};

  int lrow = l & 15, kq = l >> 4;
  int wm = w >> 1, wn = w & 1;

  auto stage = [&](int buf, int k0) {
    gll16(srcA0 + k0, &AS_(buf, s0 * 16, 0));
    gll16(srcA1 + k0, &AS_(buf, s1 * 16, 0));
    gll16(srcB0 + k0, &BS_(buf, s0 * 16, 0));
    gll16(srcB1 + k0, &BS_(buf, s1 * 16, 0));
  };
  auto compute = [&](int buf) {
    bfrag a[4], b[4];
#pragma unroll
    for (int i = 0; i < 4; ++i)
      a[i] = *(const bfrag*)&AS_(buf, wm * 64 + i * 16 + lrow, kq * 8);
#pragma unroll
    for (int j = 0; j < 4; ++j)
      b[j] = *(const bfrag*)&BS_(buf, wn * 64 + j * 16 + lrow, kq * 8);
#pragma unroll
    for (int i = 0; i < 4; ++i)
#pragma unroll
      for (int j = 0; j < 4; ++j)
        acc[i][j] = __builtin_amdgcn_mfma_f32_16x16x32_bf16(a[i], b[j], acc[i][j], 0, 0, 0);
  };

  stage(0, 0);
  __syncthreads();
  int nk = K / BK;
  int cur = 0;
  for (int kt = 0; kt < nk; ++kt) {
    if (kt + 1 < nk) stage(cur ^ 1, (kt + 1) * BK);
    compute(cur);
    __syncthreads();
    cur ^= 1;
  }

  if (GELU) {
    // stage gelu(acc+bias) as bf16 into sm[BM][BN], then stream out coalesced.
#pragma unroll
    for (int j = 0; j < 4; ++j) {
      int col = wn * 64 + j * 16 + lrow;
      float bj = bias[n0 + col];
#pragma unroll
      for (int i = 0; i < 4; ++i) {
        int rloc = wm * 64 + i * 16 + kq * 4;
#pragma unroll
        for (int r = 0; r < 4; ++r) {
          float v = acc[i][j][r] + bj;
          // tanh-form GELU, sigmoid arrangement (stable both tails):
          float z = 1.5957691216f * (v + 0.044715f * v * v * v);
          v = v / (1.0f + __expf(-z));
          sm[(rloc + r) * BN + col] = f2bf(v);
        }
      }
    }
    __syncthreads();
    // 2048 chunks of 16B; 256 threads x 8 iters; 16B/lane contiguous stores.
#pragma unroll
    for (int it = 0; it < 8; ++it) {
      int c = it * 256 + tid;
      int row = c >> 4;              // 16 chunks per 128-col row
      int cc = (c & 15) * 8;         // ushort col
      us8 v = *(const us8*)&sm[row * BN + cc];
      *(us8*)&hout[(size_t)(row0 + row) * N + n0 + cc] = v;
    }
  } else {
    int colbase = n0 + wn * 64 + lrow;
    int rowbase = row0 + wm * 64 + kq * 4;
#pragma unroll
    for (int j = 0; j < 4; ++j) {
      int col = colbase + j * 16;
      float bj = bias[col];
#pragma unroll
      for (int i = 0; i < 4; ++i) {
        int row = rowbase + i * 16;
#pragma unroll
        for (int r = 0; r < 4; ++r) {
          yout[(size_t)(row + r) * N + col] = acc[i][j][r] + bj;
        }
      }
    }
  }
#undef AS_
#undef BS_
}

// ---------------- combine ----------------
__global__ __launch_bounds__(256) void combine_kernel(const float* __restrict__ y,
                                                      const int* __restrict__ row_of,
                                                      const float* __restrict__ topw,
                                                      float* __restrict__ out) {
  int t = blockIdx.x;
  int r0 = row_of[t * 2 + 0], r1 = row_of[t * 2 + 1];
  float w0 = topw[t * 2 + 0], w1 = topw[t * 2 + 1];
  const float4* y0 = (const float4*)(y + (size_t)r0 * DDIM);
  const float4* y1 = (const float4*)(y + (size_t)r1 * DDIM);
  float4* o = (float4*)(out + (size_t)t * DDIM);
  int i = threadIdx.x;
  float4 a = y0[i], b = y1[i];
  float4 r = { w0 * a.x + w1 * b.x, w0 * a.y + w1 * b.y,
               w0 * a.z + w1 * b.z, w0 * a.w + w1 * b.w };
  o[i] = r;
}

extern "C" void kernel_launch(void* const* d_in, const int* in_sizes, int n_in,
                              void* d_out, int out_size, void* d_ws, size_t ws_size,
                              hipStream_t stream) {
  const float* x  = (const float*)d_in[0];
  const float* Wg = (const float*)d_in[1];
  const float* bg = (const float*)d_in[2];
  const float* W1 = (const float*)d_in[3];
  const float* b1 = (const float*)d_in[4];
  const float* W2 = (const float*)d_in[5];
  const float* b2 = (const float*)d_in[6];
  float* out = (float*)d_out;

  size_t off = 0;
  char* base = (char*)d_ws;
  auto alloc = [&](size_t bytes) -> void* {
    void* p = base + off;
    off += (bytes + 255) & ~(size_t)255;
    return p;
  };
  unsigned short* xb  = (unsigned short*)alloc((size_t)TOK * DDIM * 2);
  unsigned short* w1t = (unsigned short*)alloc((size_t)NEXP * HDIM * DDIM * 2);
  unsigned short* w2t = (unsigned short*)alloc((size_t)NEXP * DDIM * HDIM * 2);
  unsigned short* h   = (unsigned short*)alloc((size_t)CAP * HDIM * 2);
  float*          y   = (float*)alloc((size_t)CAP * DDIM * 4);
  int*   topi    = (int*)alloc((size_t)TOK * 2 * 4);
  float* topw    = (float*)alloc((size_t)TOK * 2 * 4);
  int*   row_of  = (int*)alloc((size_t)TOK * 2 * 4);
  int*   token_of= (int*)alloc((size_t)CAP * 4);
  int*   cnt     = (int*)alloc(32);
  int*   offsets = (int*)alloc(64);
  int*   cursor  = (int*)alloc(32);
  if (off > ws_size) return;

  hipMemsetAsync(cnt, 0, 32, stream);
  hipMemsetAsync(cursor, 0, 32, stream);
  hipMemsetAsync(token_of, 0xFF, (size_t)CAP * 4, stream);

  transpose_cvt<<<dim3(HDIM / 64, DDIM / 64, NEXP), 256, 0, stream>>>(W1, w1t, DDIM, HDIM);
  transpose_cvt<<<dim3(DDIM / 64, HDIM / 64, NEXP), 256, 0, stream>>>(W2, w2t, HDIM, DDIM);
  gate_kernel<<<TOK, 64, 0, stream>>>(x, Wg, bg, xb, topi, topw, cnt);
  scan_kernel<<<1, 64, 0, stream>>>(cnt, offsets);
  assign_kernel<<<(TOK * 2) / 256, 256, 0, stream>>>(topi, offsets, cursor, row_of, token_of);

  moe_gemm<true, true><<<dim3(HDIM / BN, NMT), 256, 0, stream>>>(
      xb, DDIM, w1t, b1, h, nullptr, HDIM, DDIM, offsets, token_of);
  moe_gemm<false, false><<<dim3(DDIM / BN, NMT), 256, 0, stream>>>(
      h, HDIM, w2t, b2, nullptr, y, DDIM, HDIM, offsets, token_of);

  combine_kernel<<<TOK, 256, 0, stream>>>(y, row_of, topw, out);
}